// Round 13
// baseline (709.902 us; speedup 1.0000x reference)
//
#include <hip/hip_runtime.h>

#define BATCH 16384
#define RT    32        // batch rows per block -> 512 blocks -> 2 blocks/CU

typedef unsigned short u16;
typedef __attribute__((ext_vector_type(8))) short short8;
typedef __attribute__((ext_vector_type(8))) _Float16 f16x8;
typedef __attribute__((ext_vector_type(4))) float f32x4;

// ---------- fp16 helpers ----------
__device__ __forceinline__ u16 f2h(float x) {
    union { _Float16 h; u16 u; } c; c.h = (_Float16)x; return c.u;
}
__device__ __forceinline__ float h2f(u16 b) {
    union { u16 u; _Float16 h; } c; c.u = b; return (float)c.h;
}
__device__ __forceinline__ unsigned int pk2(float a, float b) {
    union { __attribute__((ext_vector_type(2))) __fp16 v; unsigned int u; } c;
    c.v = __builtin_amdgcn_cvt_pkrtz(a, b);
    return c.u;
}
// 16-lane sum via DPP (verified R9/R10)
__device__ __forceinline__ float red16(float x) {
    x += __builtin_bit_cast(float, __builtin_amdgcn_update_dpp(
             0, __builtin_bit_cast(int, x), 0xB1, 0xF, 0xF, true));
    x += __builtin_bit_cast(float, __builtin_amdgcn_update_dpp(
             0, __builtin_bit_cast(int, x), 0x4E, 0xF, 0xF, true));
    x += __builtin_bit_cast(float, __builtin_amdgcn_update_dpp(
             0, __builtin_bit_cast(int, x), 0x124, 0xF, 0xF, true));
    x += __builtin_bit_cast(float, __builtin_amdgcn_update_dpp(
             0, __builtin_bit_cast(int, x), 0x128, 0xF, 0xF, true));
    return x;
}

// ================= weight pre-pack kernels (single fp16) =================
__global__ void prep_w1(const float* __restrict__ W1, const int* __restrict__ G,
                        u16* __restrict__ P) {
    int idx = blockIdx.x * 256 + threadIdx.x;   // 64*64*256 exactly
    int n = idx & 255;
    int k = (idx >> 8) & 63;
    int v = idx >> 14;
    float w = (G[k * 64 + v] > 0) ? W1[((size_t)v * 65 + k) * 256 + n] : 0.0f;
    P[(((size_t)(v * 8 + (k >> 3)) * 256 + n) << 3) + (k & 7)] = f2h(w);
}
__global__ void prep_w2(const float* __restrict__ W2, u16* __restrict__ P) {
    int idx = blockIdx.x * 256 + threadIdx.x;   // 64*256*128 exactly
    int n = idx & 127;
    int k = (idx >> 7) & 255;
    int v = idx >> 15;
    P[(((size_t)(v * 32 + (k >> 3)) * 128 + n) << 3) + (k & 7)] =
        f2h(W2[((size_t)v * 256 + k) * 128 + n]);
}

// ================= persistent fused kernel =================
// Y lives ONLY in registers as MFMA B-fragments (hi/lo fp16, 8 frags).
// v-loop unrolled 8x8 so the per-step fragment patch index jv = v&7 is a
// COMPILE-TIME constant (single static packed-element write) and global
// addresses inside the inner 8 steps are base(vb)+constant.
#define H1ST  264    // h1 stride (u16): 528B = 16 mod 128
#define YOST  68     // Yout stride (f32)

__global__ __launch_bounds__(512, 4)
void sen_fused(const float* __restrict__ U,
               const u16* __restrict__ P1, const u16* __restrict__ P2,
               const float* __restrict__ W1, const float* __restrict__ b1,
               const float* __restrict__ b2, const float* __restrict__ W3,
               const float* __restrict__ b3, float* __restrict__ Y)
{
    __shared__ __attribute__((aligned(16))) u16 h1[RT * H1ST];
    __shared__ __attribute__((aligned(16))) float yp[RT][12];  // [row][cg 0..7 +pad]
    __shared__ __attribute__((aligned(16))) float Yout[RT * YOST];

    const int tid  = threadIdx.x;
    const int row0 = blockIdx.x * RT;

    const int w  = tid >> 6, l = tid & 63;
    const int lr = l & 15,  lk = l >> 4;
    const int mg = w;   // phase 1: dim group (32 dims, W1 read once/block)
    const int cg = w;   // phase 2: col group (16 cols, W2 read once/block)

    // register-resident Y fragments: lane holds Y[row nj*16+lr][cols kt*32+lk*8 ..+8]
    f16x8 Yh[2][2], Yl[2][2];
    {
        f16x8 z;
        #pragma unroll
        for (int j = 0; j < 8; ++j) z[j] = (_Float16)0.0f;
        #pragma unroll
        for (int kt = 0; kt < 2; ++kt)
            #pragma unroll
            for (int nj = 0; nj < 2; ++nj) { Yh[kt][nj] = z; Yl[kt][nj] = z; }
    }

    #pragma unroll 1
    for (int vb = 0; vb < 8; ++vb) {
        #pragma unroll
        for (int jv = 0; jv < 8; ++jv) {
            const int v = vb * 8 + jv;

            // ---- per-step parameter loads (addresses = base(vb) + const) ----
            f32x4 b1v[2], w64v[2];
            #pragma unroll
            for (int ni = 0; ni < 2; ++ni) {
                const int dim = mg * 32 + ni * 16 + lk * 4;
                b1v[ni]  = *(const f32x4*)(b1 + v * 256 + dim);
                w64v[ni] = *(const f32x4*)(W1 + ((size_t)v * 65 + 64) * 256 + dim);
            }
            float u_c[2];
            #pragma unroll
            for (int nj = 0; nj < 2; ++nj)
                u_c[nj] = U[(size_t)(row0 + nj * 16 + lr) * 64 + v];
            const float b2c = b2[v * 128 + cg * 16 + lr];
            const float w3c = W3[v * 128 + cg * 16 + lr];
            const float b3v = b3[v];

            // ======== Phase 1 — Layer 1 (operand-swapped), Y from registers ====
            f32x4 acc1[2][2];
            #pragma unroll
            for (int nj = 0; nj < 2; ++nj)
                #pragma unroll
                for (int ni = 0; ni < 2; ++ni) acc1[nj][ni] = (f32x4){0.f, 0.f, 0.f, 0.f};

            #pragma unroll
            for (int kt = 0; kt < 2; ++kt)
                #pragma unroll
                for (int ni = 0; ni < 2; ++ni) {
                    const f16x8 Wf = *(const f16x8*)&P1[
                        (((size_t)(v * 8 + kt * 4 + lk) * 256) + mg * 32 + ni * 16 + lr) << 3];
                    #pragma unroll
                    for (int nj = 0; nj < 2; ++nj) {
                        acc1[nj][ni] = __builtin_amdgcn_mfma_f32_16x16x32_f16(Wf, Yh[kt][nj], acc1[nj][ni], 0, 0, 0);
                        acc1[nj][ni] = __builtin_amdgcn_mfma_f32_16x16x32_f16(Wf, Yl[kt][nj], acc1[nj][ni], 0, 0, 0);
                    }
                }
            // epilogue: + bias + u * W1[64,:] (exact fp32), relu, fp16 pack, store
            #pragma unroll
            for (int nj = 0; nj < 2; ++nj) {
                const int brow = nj * 16 + lr;
                #pragma unroll
                for (int ni = 0; ni < 2; ++ni) {
                    float x[4];
                    #pragma unroll
                    for (int r = 0; r < 4; ++r)
                        x[r] = fmaxf(acc1[nj][ni][r] + b1v[ni][r] + u_c[nj] * w64v[ni][r], 0.0f);
                    unsigned long long pk = (unsigned long long)pk2(x[0], x[1])
                                          | ((unsigned long long)pk2(x[2], x[3]) << 32);
                    *(unsigned long long*)&h1[brow * H1ST + mg * 32 + ni * 16 + lk * 4] = pk;
                }
            }
            __syncthreads();   // B1: h1 written -> phase 2 may read

            // ======== Phase 2 — Layer 2 (bias via acc init) + in-reg layer 3 ====
            f32x4 acc2[2];
            acc2[0] = (f32x4){b2c, b2c, b2c, b2c};
            acc2[1] = acc2[0];
            #pragma unroll
            for (int kt = 0; kt < 8; ++kt) {
                const f16x8 Bf = *(const f16x8*)&P2[
                    (((size_t)(v * 32 + kt * 4 + lk) * 128) + cg * 16 + lr) << 3];
                #pragma unroll
                for (int mi = 0; mi < 2; ++mi) {
                    const f16x8 Hf = *(const f16x8*)&h1[(mi * 16 + lr) * H1ST + kt * 32 + lk * 8];
                    acc2[mi] = __builtin_amdgcn_mfma_f32_16x16x32_f16(Hf, Bf, acc2[mi], 0, 0, 0);
                }
            }
            // layer-3 partials: relu * w3, DPP-reduce over 16 col-lanes
            #pragma unroll
            for (int mi = 0; mi < 2; ++mi) {
                float s0 = red16(fmaxf(acc2[mi][0], 0.0f) * w3c);
                float s1 = red16(fmaxf(acc2[mi][1], 0.0f) * w3c);
                float s2 = red16(fmaxf(acc2[mi][2], 0.0f) * w3c);
                float s3 = red16(fmaxf(acc2[mi][3], 0.0f) * w3c);
                if (lr == 0) {
                    const int row = mi * 16 + lk * 4;
                    yp[row + 0][cg] = s0;
                    yp[row + 1][cg] = s1;
                    yp[row + 2][cg] = s2;
                    yp[row + 3][cg] = s3;
                }
            }
            __syncthreads();   // B2: yp complete

            // ======== per-lane y compute + register patch (static jv) ========
            float y[2];
            #pragma unroll
            for (int nj = 0; nj < 2; ++nj) {
                const int row = nj * 16 + lr;
                const f32x4 a = *(const f32x4*)&yp[row][0];
                const f32x4 b = *(const f32x4*)&yp[row][4];
                // fixed left-to-right order -> identical value in every lane/wave
                y[nj] = b3v + a[0] + a[1] + a[2] + a[3] + b[0] + b[1] + b[2] + b[3];
            }
            if (w == 0 && lk == 0) {
                Yout[lr * YOST + v]        = y[0];
                Yout[(16 + lr) * YOST + v] = y[1];
            }
            const _Float16 yh0 = (_Float16)y[0];
            const _Float16 yl0 = (_Float16)(y[0] - (float)yh0);
            const _Float16 yh1 = (_Float16)y[1];
            const _Float16 yl1 = (_Float16)(y[1] - (float)yh1);
            if ((vb & 3) == lk) {               // uniform-per-lane compare, 1 op
                if (vb < 4) {                   // scalar-uniform arm select
                    if (true) {                 // static element index jv
                        Yh[0][0][jv] = yh0; Yl[0][0][jv] = yl0;
                        Yh[0][1][jv] = yh1; Yl[0][1][jv] = yl1;
                    }
                } else {
                    Yh[1][0][jv] = yh0; Yl[1][0][jv] = yl0;
                    Yh[1][1][jv] = yh1; Yl[1][1][jv] = yl1;
                }
            }
            // h1/yp reuse fenced by next step's B1/B2; Yout read only after loop.
        }
    }
    __syncthreads();   // Yout complete

    // ---- final coalesced store (exact f32), 1 float4 per thread ----
    {
        const int row = tid >> 4, c4 = (tid & 15) * 4;
        *(float4*)(Y + (size_t)(row0 + row) * 64 + c4) = *(float4*)&Yout[row * YOST + c4];
    }
}

extern "C" void kernel_launch(void* const* d_in, const int* in_sizes, int n_in,
                              void* d_out, int out_size, void* d_ws, size_t ws_size,
                              hipStream_t stream) {
    // inputs: X, U, causal_graph, W1, b1, W2, b2, W3, b3  (X never feeds the recursion)
    const float* U  = (const float*)d_in[1];
    const int*   G  = (const int*)  d_in[2];
    const float* W1 = (const float*)d_in[3];
    const float* b1 = (const float*)d_in[4];
    const float* W2 = (const float*)d_in[5];
    const float* b2 = (const float*)d_in[6];
    const float* W3 = (const float*)d_in[7];
    const float* b3 = (const float*)d_in[8];
    float* Y = (float*)d_out;

    const size_t S1 = (size_t)64 * 64 * 256;     // u16 elements, packed W1
    u16* P1 = (u16*)d_ws;
    u16* P2 = P1 + S1;

    prep_w1<<<(64 * 64 * 256) / 256, 256, 0, stream>>>(W1, G, P1);
    prep_w2<<<(64 * 256 * 128) / 256, 256, 0, stream>>>(W2, P2);
    sen_fused<<<BATCH / RT, 512, 0, stream>>>(U, P1, P2, W1, b1, b2, W3, b3, Y);
}

// Round 14
// 285.032 us; speedup vs baseline: 2.4906x; 2.4906x over previous
//
#include <hip/hip_runtime.h>

#define BATCH 16384
#define RT    32        // batch rows per block -> 512 blocks -> 2 blocks/CU

typedef unsigned short u16;
typedef __attribute__((ext_vector_type(8))) short short8;
typedef __attribute__((ext_vector_type(8))) _Float16 f16x8;
typedef __attribute__((ext_vector_type(4))) float f32x4;

// ---------- fp16 helpers ----------
__device__ __forceinline__ u16 f2h(float x) {
    union { _Float16 h; u16 u; } c; c.h = (_Float16)x; return c.u;
}
__device__ __forceinline__ float h2f(u16 b) {
    union { u16 u; _Float16 h; } c; c.u = b; return (float)c.h;
}
__device__ __forceinline__ unsigned int pk2(float a, float b) {
    union { __attribute__((ext_vector_type(2))) __fp16 v; unsigned int u; } c;
    c.v = __builtin_amdgcn_cvt_pkrtz(a, b);
    return c.u;
}
// 16-lane sum via DPP (verified R9/R10)
__device__ __forceinline__ float red16(float x) {
    x += __builtin_bit_cast(float, __builtin_amdgcn_update_dpp(
             0, __builtin_bit_cast(int, x), 0xB1, 0xF, 0xF, true));
    x += __builtin_bit_cast(float, __builtin_amdgcn_update_dpp(
             0, __builtin_bit_cast(int, x), 0x4E, 0xF, 0xF, true));
    x += __builtin_bit_cast(float, __builtin_amdgcn_update_dpp(
             0, __builtin_bit_cast(int, x), 0x124, 0xF, 0xF, true));
    x += __builtin_bit_cast(float, __builtin_amdgcn_update_dpp(
             0, __builtin_bit_cast(int, x), 0x128, 0xF, 0xF, true));
    return x;
}

// ================= weight pre-pack kernels (single fp16) =================
// prep_w1: STRICT premask k <= v-2 (newest possible parent k=v-1 handled
// in-kernel as a VALU rank-1 term, enabling lazy Y-column finalize).
__global__ void prep_w1(const float* __restrict__ W1, const int* __restrict__ G,
                        u16* __restrict__ P) {
    int idx = blockIdx.x * 256 + threadIdx.x;   // 64*64*256 exactly
    int n = idx & 255;
    int k = (idx >> 8) & 63;
    int v = idx >> 14;
    float w = (k + 1 < v && G[k * 64 + v] > 0) ? W1[((size_t)v * 65 + k) * 256 + n] : 0.0f;
    P[(((size_t)(v * 8 + (k >> 3)) * 256 + n) << 3) + (k & 7)] = f2h(w);
}
// Wp[v][n] = G[v-1][v] ? W1[v][k=v-1][n] : 0   (fp16, 32 KB, L2-resident)
__global__ void prep_wp1(const float* __restrict__ W1, const int* __restrict__ G,
                         u16* __restrict__ P) {
    int n = threadIdx.x;
    int v = blockIdx.x;
    float w = (v >= 1 && G[(v - 1) * 64 + v] > 0)
                  ? W1[((size_t)v * 65 + (v - 1)) * 256 + n] : 0.0f;
    P[v * 256 + n] = f2h(w);
}
__global__ void prep_w2(const float* __restrict__ W2, u16* __restrict__ P) {
    int idx = blockIdx.x * 256 + threadIdx.x;   // 64*256*128 exactly
    int n = idx & 127;
    int k = (idx >> 7) & 255;
    int v = idx >> 15;
    P[(((size_t)(v * 32 + (k >> 3)) * 128 + n) << 3) + (k & 7)] =
        f2h(W2[((size_t)v * 256 + k) * 128 + n]);
}

// ================= persistent fused kernel =================
// 2 barriers/step. Y tile: SINGLE fp16 (quant error budgeted). Output in
// exact f32 via Yout. Y col v-1 written lazily pre-B1 of step v (concurrent
// phase-1 reads hit a guaranteed-zero weight; zero-init -> never NaN).
#define AST   72     // Y-tile stride (u16): 144B = 16 mod 128
#define H1ST  264    // h1 stride (u16): 528B = 16 mod 128
#define YOST  68     // Yout stride (f32)

__global__ __launch_bounds__(512, 4)
void sen_fused(const float* __restrict__ U,
               const u16* __restrict__ P1, const u16* __restrict__ P2,
               const u16* __restrict__ Wp,
               const float* __restrict__ W1, const float* __restrict__ b1,
               const float* __restrict__ b2, const float* __restrict__ W3,
               const float* __restrict__ b3, float* __restrict__ Y)
{
    __shared__ __attribute__((aligned(16))) u16 Ay[RT * AST];
    __shared__ __attribute__((aligned(16))) u16 h1[RT * H1ST];
    __shared__ __attribute__((aligned(16))) float yp[RT][12];  // [row][cg]+pad
    __shared__ __attribute__((aligned(16))) float Yout[RT * YOST];

    const int tid  = threadIdx.x;
    const int row0 = blockIdx.x * RT;

    // zero-init Y tile AND yp (v=0 reads yp; must be finite)
    {
        short8 z = {0,0,0,0,0,0,0,0};
        for (int i = tid; i < (RT * AST) / 8; i += 512)
            *(short8*)&Ay[i * 8] = z;
        if (tid < RT * 12) ((float*)yp)[tid] = 0.0f;
    }
    __syncthreads();

    const int w  = tid >> 6, l = tid & 63;
    const int lr = l & 15,  lk = l >> 4;
    const int mg = w;   // phase 1: dim group (32 dims, W1 read once/block)
    const int cg = w;   // phase 2: col group (16 cols, W2 read once/block)

    #pragma unroll 1
    for (int v = 0; v < 64; ++v) {
        // ======== prologue (pre-B1) ========
        f32x4 b1v[2], w64v[2], wpv[2];
        #pragma unroll
        for (int ni = 0; ni < 2; ++ni) {
            const int dim = mg * 32 + ni * 16 + lk * 4;
            b1v[ni]  = *(const f32x4*)(b1 + v * 256 + dim);
            w64v[ni] = *(const f32x4*)(W1 + ((size_t)v * 65 + 64) * 256 + dim);
            const u16* wp = &Wp[v * 256 + dim];
            wpv[ni] = (f32x4){h2f(wp[0]), h2f(wp[1]), h2f(wp[2]), h2f(wp[3])};
        }
        float u_c[2];
        #pragma unroll
        for (int nj = 0; nj < 2; ++nj)
            u_c[nj] = U[(size_t)(row0 + nj * 16 + lr) * 64 + v];
        const float b2c = b2[v * 128 + cg * 16 + lr];
        const float w3c = W3[v * 128 + cg * 16 + lr];
        const float b3p = b3[(v > 0) ? (v - 1) : 0];

        // y_{v-1} recomputed per-lane from yp (fixed order -> identical everywhere)
        float yprev[2];
        #pragma unroll
        for (int nj = 0; nj < 2; ++nj) {
            const int row = nj * 16 + lr;
            const f32x4 a = *(const f32x4*)&yp[row][0];
            const f32x4 b = *(const f32x4*)&yp[row][4];
            yprev[nj] = b3p + a[0] + a[1] + a[2] + a[3] + b[0] + b[1] + b[2] + b[3];
        }
        // lazy finalize of col v-1 (zero weight this step -> race-free)
        if (v > 0 && w == 0 && lk == 0) {
            Ay[lr * AST + (v - 1)]        = f2h(yprev[0]);
            Ay[(16 + lr) * AST + (v - 1)] = f2h(yprev[1]);
            Yout[lr * YOST + (v - 1)]        = yprev[0];
            Yout[(16 + lr) * YOST + (v - 1)] = yprev[1];
        }

        // ======== Phase 1 — Layer 1 (operand-swapped, strict mask) ========
        f32x4 acc1[2][2];
        #pragma unroll
        for (int nj = 0; nj < 2; ++nj)
            #pragma unroll
            for (int ni = 0; ni < 2; ++ni) acc1[nj][ni] = (f32x4){0.f, 0.f, 0.f, 0.f};

        #pragma unroll
        for (int kt = 0; kt < 2; ++kt) {
            f16x8 Yf[2];
            #pragma unroll
            for (int nj = 0; nj < 2; ++nj)
                Yf[nj] = *(const f16x8*)&Ay[(nj * 16 + lr) * AST + kt * 32 + lk * 8];
            #pragma unroll
            for (int ni = 0; ni < 2; ++ni) {
                const f16x8 Wf = *(const f16x8*)&P1[
                    (((size_t)(v * 8 + kt * 4 + lk) * 256) + mg * 32 + ni * 16 + lr) << 3];
                #pragma unroll
                for (int nj = 0; nj < 2; ++nj)
                    acc1[nj][ni] = __builtin_amdgcn_mfma_f32_16x16x32_f16(Wf, Yf[nj], acc1[nj][ni], 0, 0, 0);
            }
        }
        // epilogue: + b1 + u*W1[64,:] + y_{v-1}*Wp (all fp32), relu, pack, store
        #pragma unroll
        for (int nj = 0; nj < 2; ++nj) {
            const int brow = nj * 16 + lr;
            #pragma unroll
            for (int ni = 0; ni < 2; ++ni) {
                float x[4];
                #pragma unroll
                for (int r = 0; r < 4; ++r)
                    x[r] = fmaxf(acc1[nj][ni][r] + b1v[ni][r]
                                 + u_c[nj] * w64v[ni][r]
                                 + yprev[nj] * wpv[ni][r], 0.0f);
                unsigned long long pk = (unsigned long long)pk2(x[0], x[1])
                                      | ((unsigned long long)pk2(x[2], x[3]) << 32);
                *(unsigned long long*)&h1[brow * H1ST + mg * 32 + ni * 16 + lk * 4] = pk;
            }
        }
        __syncthreads();   // B1: h1 + lazy col v-1 visible

        // ======== Phase 2 — Layer 2 (bias via acc init) + in-reg layer 3 ========
        f32x4 acc2[2];
        acc2[0] = (f32x4){b2c, b2c, b2c, b2c};
        acc2[1] = acc2[0];
        #pragma unroll
        for (int kt = 0; kt < 8; ++kt) {
            const f16x8 Bf = *(const f16x8*)&P2[
                (((size_t)(v * 32 + kt * 4 + lk) * 128) + cg * 16 + lr) << 3];
            #pragma unroll
            for (int mi = 0; mi < 2; ++mi) {
                const f16x8 Hf = *(const f16x8*)&h1[(mi * 16 + lr) * H1ST + kt * 32 + lk * 8];
                acc2[mi] = __builtin_amdgcn_mfma_f32_16x16x32_f16(Hf, Bf, acc2[mi], 0, 0, 0);
            }
        }
        // layer-3 partials: relu * w3, DPP-reduce over 16 col-lanes
        #pragma unroll
        for (int mi = 0; mi < 2; ++mi) {
            float s0 = red16(fmaxf(acc2[mi][0], 0.0f) * w3c);
            float s1 = red16(fmaxf(acc2[mi][1], 0.0f) * w3c);
            float s2 = red16(fmaxf(acc2[mi][2], 0.0f) * w3c);
            float s3 = red16(fmaxf(acc2[mi][3], 0.0f) * w3c);
            if (lr == 0) {
                const int row = mi * 16 + lk * 4;
                yp[row + 0][cg] = s0;
                yp[row + 1][cg] = s1;
                yp[row + 2][cg] = s2;
                yp[row + 3][cg] = s3;
            }
        }
        __syncthreads();   // B2: yp complete (fences next prologue's yp reads)
    }

    // ---- y_63 from final yp, then coalesced f32 store ----
    if (w == 0 && lk == 0) {
        #pragma unroll
        for (int nj = 0; nj < 2; ++nj) {
            const int row = nj * 16 + lr;
            const f32x4 a = *(const f32x4*)&yp[row][0];
            const f32x4 b = *(const f32x4*)&yp[row][4];
            Yout[row * YOST + 63] =
                b3[63] + a[0] + a[1] + a[2] + a[3] + b[0] + b[1] + b[2] + b[3];
        }
    }
    __syncthreads();
    {
        const int row = tid >> 4, c4 = (tid & 15) * 4;
        *(float4*)(Y + (size_t)(row0 + row) * 64 + c4) = *(float4*)&Yout[row * YOST + c4];
    }
}

extern "C" void kernel_launch(void* const* d_in, const int* in_sizes, int n_in,
                              void* d_out, int out_size, void* d_ws, size_t ws_size,
                              hipStream_t stream) {
    // inputs: X, U, causal_graph, W1, b1, W2, b2, W3, b3  (X never feeds the recursion)
    const float* U  = (const float*)d_in[1];
    const int*   G  = (const int*)  d_in[2];
    const float* W1 = (const float*)d_in[3];
    const float* b1 = (const float*)d_in[4];
    const float* W2 = (const float*)d_in[5];
    const float* b2 = (const float*)d_in[6];
    const float* W3 = (const float*)d_in[7];
    const float* b3 = (const float*)d_in[8];
    float* Y = (float*)d_out;

    const size_t S1 = (size_t)64 * 64 * 256;     // u16, packed strict W1
    const size_t S2 = (size_t)64 * 256 * 128;    // u16, packed W2
    u16* P1 = (u16*)d_ws;
    u16* P2 = P1 + S1;
    u16* Wp = P2 + S2;                           // 64*256 u16

    prep_w1<<<(64 * 64 * 256) / 256, 256, 0, stream>>>(W1, G, P1);
    prep_w2<<<(64 * 256 * 128) / 256, 256, 0, stream>>>(W2, P2);
    prep_wp1<<<64, 256, 0, stream>>>(W1, G, Wp);
    sen_fused<<<BATCH / RT, 512, 0, stream>>>(U, P1, P2, Wp, W1, b1, b2, W3, b3, Y);
}

// Round 15
// 256.607 us; speedup vs baseline: 2.7665x; 1.1108x over previous
//
#include <hip/hip_runtime.h>

#define BATCH 16384
#define RT    32        // batch rows per block -> 512 blocks -> 2 blocks/CU

typedef unsigned short u16;
typedef __attribute__((ext_vector_type(8))) short short8;
typedef __attribute__((ext_vector_type(8))) _Float16 f16x8;
typedef __attribute__((ext_vector_type(4))) float f32x4;

// ---------- fp16 helpers ----------
__device__ __forceinline__ u16 f2h(float x) {
    union { _Float16 h; u16 u; } c; c.h = (_Float16)x; return c.u;
}
__device__ __forceinline__ float h2f(u16 b) {
    union { u16 u; _Float16 h; } c; c.u = b; return (float)c.h;
}
__device__ __forceinline__ unsigned int pk2(float a, float b) {
    union { __attribute__((ext_vector_type(2))) __fp16 v; unsigned int u; } c;
    c.v = __builtin_amdgcn_cvt_pkrtz(a, b);
    return c.u;
}
// 16-lane sum via DPP (verified R9/R10)
__device__ __forceinline__ float red16(float x) {
    x += __builtin_bit_cast(float, __builtin_amdgcn_update_dpp(
             0, __builtin_bit_cast(int, x), 0xB1, 0xF, 0xF, true));
    x += __builtin_bit_cast(float, __builtin_amdgcn_update_dpp(
             0, __builtin_bit_cast(int, x), 0x4E, 0xF, 0xF, true));
    x += __builtin_bit_cast(float, __builtin_amdgcn_update_dpp(
             0, __builtin_bit_cast(int, x), 0x124, 0xF, 0xF, true));
    x += __builtin_bit_cast(float, __builtin_amdgcn_update_dpp(
             0, __builtin_bit_cast(int, x), 0x128, 0xF, 0xF, true));
    return x;
}

// ================= weight pre-pack kernels (single fp16) =================
// prep_w1: STRICT premask k <= v-2 (newest possible parent k=v-1 handled
// in-kernel as a VALU rank-1 term). This makes step v+1's MFMA part
// independent of step v's phase 2 -> cross-step pipelining.
__global__ void prep_w1(const float* __restrict__ W1, const int* __restrict__ G,
                        u16* __restrict__ P) {
    int idx = blockIdx.x * 256 + threadIdx.x;   // 64*64*256 exactly
    int n = idx & 255;
    int k = (idx >> 8) & 63;
    int v = idx >> 14;
    float w = (k + 1 < v && G[k * 64 + v] > 0) ? W1[((size_t)v * 65 + k) * 256 + n] : 0.0f;
    P[(((size_t)(v * 8 + (k >> 3)) * 256 + n) << 3) + (k & 7)] = f2h(w);
}
// Wp[v][n] = G[v-1][v] ? W1[v][k=v-1][n] : 0   (fp16, 32 KB, L2-resident)
__global__ void prep_wp1(const float* __restrict__ W1, const int* __restrict__ G,
                         u16* __restrict__ P) {
    int n = threadIdx.x;
    int v = blockIdx.x;
    float w = (v >= 1 && G[(v - 1) * 64 + v] > 0)
                  ? W1[((size_t)v * 65 + (v - 1)) * 256 + n] : 0.0f;
    P[v * 256 + n] = f2h(w);
}
__global__ void prep_w2(const float* __restrict__ W2, u16* __restrict__ P) {
    int idx = blockIdx.x * 256 + threadIdx.x;   // 64*256*128 exactly
    int n = idx & 127;
    int k = (idx >> 7) & 255;
    int v = idx >> 15;
    P[(((size_t)(v * 32 + (k >> 3)) * 128 + n) << 3) + (k & 7)] =
        f2h(W2[((size_t)v * 256 + k) * 128 + n]);
}

// ================= persistent fused kernel =================
// Cross-step pipeline, 2 barriers/step:
//   segB: epilogue(v)  = yprev + rank-1 + relu -> h1 writes           | B1
//   segA: phase2(v) MFMAs + yp  ||  phase1-MFMA(v+1) + param loads    | B2
// phase1-MFMA(v+1) reads Ay cols <= v-1 only (strict mask): col v-1
// written in segB(v) pre-B1 (fenced); col v is zero-weighted (stale-read
// benign, always finite).
#define AST   72     // Y-tile stride (u16): 144B = 16 mod 128
#define H1ST  264    // h1 stride (u16): 528B = 16 mod 128
#define YOST  68     // Yout stride (f32)

__global__ __launch_bounds__(512, 4)
void sen_fused(const float* __restrict__ U,
               const u16* __restrict__ P1, const u16* __restrict__ P2,
               const u16* __restrict__ Wp,
               const float* __restrict__ W1, const float* __restrict__ b1,
               const float* __restrict__ b2, const float* __restrict__ W3,
               const float* __restrict__ b3, float* __restrict__ Y)
{
    __shared__ __attribute__((aligned(16))) u16 Ay[RT * AST];
    __shared__ __attribute__((aligned(16))) u16 h1[RT * H1ST];
    __shared__ __attribute__((aligned(16))) float yp[RT][12];  // [row][cg]+pad
    __shared__ __attribute__((aligned(16))) float Yout[RT * YOST];

    const int tid  = threadIdx.x;
    const int row0 = blockIdx.x * RT;

    // zero-init Y tile AND yp (v=0 prologue reads yp; must be finite)
    {
        short8 z = {0,0,0,0,0,0,0,0};
        for (int i = tid; i < (RT * AST) / 8; i += 512)
            *(short8*)&Ay[i * 8] = z;
        if (tid < RT * 12) ((float*)yp)[tid] = 0.0f;
    }
    __syncthreads();

    const int w  = tid >> 6, l = tid & 63;
    const int lr = l & 15,  lk = l >> 4;
    const int mg = w;   // phase 1: dim group (32 dims, W1 read once/block)
    const int cg = w;   // phase 2: col group (16 cols, W2 read once/block)

    // ---- bootstrap params for v=0; acc1 pre-initialized with b1 ----
    f32x4 acc1[2][2], w64v[2], wpv[2];
    float u_c[2], b2c, w3c, b3p;
    {
        #pragma unroll
        for (int ni = 0; ni < 2; ++ni) {
            const int dim = mg * 32 + ni * 16 + lk * 4;
            const f32x4 b1v = *(const f32x4*)(b1 + dim);
            acc1[0][ni] = b1v;          // strict mask(0) is empty -> no MFMA
            acc1[1][ni] = b1v;
            w64v[ni] = *(const f32x4*)(W1 + (size_t)64 * 256 + dim);
            const u16* wp = &Wp[dim];
            wpv[ni] = (f32x4){h2f(wp[0]), h2f(wp[1]), h2f(wp[2]), h2f(wp[3])};
        }
        u_c[0] = U[(size_t)(row0 + lr) * 64];
        u_c[1] = U[(size_t)(row0 + 16 + lr) * 64];
        b2c = b2[cg * 16 + lr];
        w3c = W3[cg * 16 + lr];
        b3p = 0.0f;   // y_{-1} unused (wpv(0)=0), just needs to be finite
    }

    #pragma unroll 1
    for (int v = 0; v < 64; ++v) {
        // ======== SEGMENT B: finish phase 1 of step v ========
        float yprev[2];
        #pragma unroll
        for (int nj = 0; nj < 2; ++nj) {
            const int row = nj * 16 + lr;
            const f32x4 a = *(const f32x4*)&yp[row][0];
            const f32x4 b = *(const f32x4*)&yp[row][4];
            yprev[nj] = b3p + a[0] + a[1] + a[2] + a[3] + b[0] + b[1] + b[2] + b[3];
        }
        if (v > 0 && w == 0 && lk == 0) {   // lazy finalize col v-1
            Ay[lr * AST + (v - 1)]        = f2h(yprev[0]);
            Ay[(16 + lr) * AST + (v - 1)] = f2h(yprev[1]);
            Yout[lr * YOST + (v - 1)]        = yprev[0];
            Yout[(16 + lr) * YOST + (v - 1)] = yprev[1];
        }
        // epilogue: acc1 already holds (W1_strict @ Y + b1); add rank-1 terms
        #pragma unroll
        for (int nj = 0; nj < 2; ++nj) {
            const int brow = nj * 16 + lr;
            #pragma unroll
            for (int ni = 0; ni < 2; ++ni) {
                float x[4];
                #pragma unroll
                for (int r = 0; r < 4; ++r)
                    x[r] = fmaxf(acc1[nj][ni][r]
                                 + u_c[nj] * w64v[ni][r]
                                 + yprev[nj] * wpv[ni][r], 0.0f);
                unsigned long long pk = (unsigned long long)pk2(x[0], x[1])
                                      | ((unsigned long long)pk2(x[2], x[3]) << 32);
                *(unsigned long long*)&h1[brow * H1ST + mg * 32 + ni * 16 + lk * 4] = pk;
            }
        }
        __syncthreads();   // B1: h1 + Ay col v-1 visible

        // ======== SEGMENT A: phase2(v)  ||  phase1-MFMA(v+1) ========
        // --- phase 2 (step v) ---
        f32x4 acc2[2];
        acc2[0] = (f32x4){b2c, b2c, b2c, b2c};
        acc2[1] = acc2[0];
        #pragma unroll
        for (int kt = 0; kt < 8; ++kt) {
            const f16x8 Bf = *(const f16x8*)&P2[
                (((size_t)(v * 32 + kt * 4 + lk) * 128) + cg * 16 + lr) << 3];
            #pragma unroll
            for (int mi = 0; mi < 2; ++mi) {
                const f16x8 Hf = *(const f16x8*)&h1[(mi * 16 + lr) * H1ST + kt * 32 + lk * 8];
                acc2[mi] = __builtin_amdgcn_mfma_f32_16x16x32_f16(Hf, Bf, acc2[mi], 0, 0, 0);
            }
        }
        #pragma unroll
        for (int mi = 0; mi < 2; ++mi) {
            float s0 = red16(fmaxf(acc2[mi][0], 0.0f) * w3c);
            float s1 = red16(fmaxf(acc2[mi][1], 0.0f) * w3c);
            float s2 = red16(fmaxf(acc2[mi][2], 0.0f) * w3c);
            float s3 = red16(fmaxf(acc2[mi][3], 0.0f) * w3c);
            if (lr == 0) {
                const int row = mi * 16 + lk * 4;
                yp[row + 0][cg] = s0;
                yp[row + 1][cg] = s1;
                yp[row + 2][cg] = s2;
                yp[row + 3][cg] = s3;
            }
        }
        // --- phase 1 MFMA for step v+1 (independent of phase 2 above) ---
        if (v < 63) {
            const int vn = v + 1;
            f32x4 nw64[2], nwp[2];
            #pragma unroll
            for (int ni = 0; ni < 2; ++ni) {
                const int dim = mg * 32 + ni * 16 + lk * 4;
                const f32x4 nb1 = *(const f32x4*)(b1 + vn * 256 + dim);
                acc1[0][ni] = nb1;
                acc1[1][ni] = nb1;
                nw64[ni] = *(const f32x4*)(W1 + ((size_t)vn * 65 + 64) * 256 + dim);
                const u16* wp = &Wp[vn * 256 + dim];
                nwp[ni] = (f32x4){h2f(wp[0]), h2f(wp[1]), h2f(wp[2]), h2f(wp[3])};
            }
            #pragma unroll
            for (int kt = 0; kt < 2; ++kt) {
                f16x8 Yf[2];
                #pragma unroll
                for (int nj = 0; nj < 2; ++nj)
                    Yf[nj] = *(const f16x8*)&Ay[(nj * 16 + lr) * AST + kt * 32 + lk * 8];
                #pragma unroll
                for (int ni = 0; ni < 2; ++ni) {
                    const f16x8 Wf = *(const f16x8*)&P1[
                        (((size_t)(vn * 8 + kt * 4 + lk) * 256) + mg * 32 + ni * 16 + lr) << 3];
                    #pragma unroll
                    for (int nj = 0; nj < 2; ++nj)
                        acc1[nj][ni] = __builtin_amdgcn_mfma_f32_16x16x32_f16(Wf, Yf[nj], acc1[nj][ni], 0, 0, 0);
                }
            }
            // rotate params for step v+1
            u_c[0] = U[(size_t)(row0 + lr) * 64 + vn];
            u_c[1] = U[(size_t)(row0 + 16 + lr) * 64 + vn];
            b2c = b2[vn * 128 + cg * 16 + lr];
            w3c = W3[vn * 128 + cg * 16 + lr];
            b3p = b3[v];
            w64v[0] = nw64[0]; w64v[1] = nw64[1];
            wpv[0]  = nwp[0];  wpv[1]  = nwp[1];
        }
        __syncthreads();   // B2: yp complete; h1 free for next step
    }

    // ---- y_63 from final yp, then coalesced f32 store ----
    if (w == 0 && lk == 0) {
        #pragma unroll
        for (int nj = 0; nj < 2; ++nj) {
            const int row = nj * 16 + lr;
            const f32x4 a = *(const f32x4*)&yp[row][0];
            const f32x4 b = *(const f32x4*)&yp[row][4];
            Yout[row * YOST + 63] =
                b3[63] + a[0] + a[1] + a[2] + a[3] + b[0] + b[1] + b[2] + b[3];
        }
    }
    __syncthreads();
    {
        const int row = tid >> 4, c4 = (tid & 15) * 4;
        *(float4*)(Y + (size_t)(row0 + row) * 64 + c4) = *(float4*)&Yout[row * YOST + c4];
    }
}

extern "C" void kernel_launch(void* const* d_in, const int* in_sizes, int n_in,
                              void* d_out, int out_size, void* d_ws, size_t ws_size,
                              hipStream_t stream) {
    // inputs: X, U, causal_graph, W1, b1, W2, b2, W3, b3  (X never feeds the recursion)
    const float* U  = (const float*)d_in[1];
    const int*   G  = (const int*)  d_in[2];
    const float* W1 = (const float*)d_in[3];
    const float* b1 = (const float*)d_in[4];
    const float* W2 = (const float*)d_in[5];
    const float* b2 = (const float*)d_in[6];
    const float* W3 = (const float*)d_in[7];
    const float* b3 = (const float*)d_in[8];
    float* Y = (float*)d_out;

    const size_t S1 = (size_t)64 * 64 * 256;     // u16, packed strict W1
    const size_t S2 = (size_t)64 * 256 * 128;    // u16, packed W2
    u16* P1 = (u16*)d_ws;
    u16* P2 = P1 + S1;
    u16* Wp = P2 + S2;                           // 64*256 u16

    prep_w1<<<(64 * 64 * 256) / 256, 256, 0, stream>>>(W1, G, P1);
    prep_w2<<<(64 * 256 * 128) / 256, 256, 0, stream>>>(W2, P2);
    prep_wp1<<<64, 256, 0, stream>>>(W1, G, Wp);
    sen_fused<<<BATCH / RT, 512, 0, stream>>>(U, P1, P2, Wp, W1, b1, b2, W3, b3, Y);
}